// Round 1
// baseline (1386.814 us; speedup 1.0000x reference)
//
#include <hip/hip_runtime.h>

#define T_TOT 262144
#define S_DIM 512
#define A_DIM 64
#define GAMMA 0.99f
#define GL 0.9702f    /* gamma*lam in f32, matching f64->f32 rounding of 0.99*0.98 */
#define CLIP_LO 0.8f
#define CLIP_HI 1.2f
#define ENT_COEF 0.01f

typedef __bf16 bf16_t;
typedef bf16_t bf16x8 __attribute__((ext_vector_type(8)));
typedef float f32x4 __attribute__((ext_vector_type(4)));

#define LDBT 520   /* bf16 elems per Bt row: 512 + 8 pad -> conflict-free phase pattern */

__device__ __forceinline__ float dot4(f32x4 a, f32x4 b) {
  return a.x * b.x + a.y * b.y + a.z * b.z + a.w * b.w;
}
__device__ __forceinline__ f32x4 vmax4(f32x4 a, f32x4 b) {
  f32x4 r; r.x = fmaxf(a.x, b.x); r.y = fmaxf(a.y, b.y);
  r.z = fmaxf(a.z, b.z); r.w = fmaxf(a.w, b.w); return r;
}
__device__ __forceinline__ f32x4 shflx4(f32x4 v, int m) {
  f32x4 r; r.x = __shfl_xor(v.x, m, 64); r.y = __shfl_xor(v.y, m, 64);
  r.z = __shfl_xor(v.z, m, 64); r.w = __shfl_xor(v.w, m, 64); return r;
}
__device__ __forceinline__ f32x4 exp4(f32x4 v) {
  f32x4 r; r.x = __expf(v.x); r.y = __expf(v.y);
  r.z = __expf(v.z); r.w = __expf(v.w); return r;
}
__device__ __forceinline__ f32x4 log4(f32x4 v) {
  f32x4 r; r.x = __logf(v.x); r.y = __logf(v.y);
  r.z = __logf(v.z); r.w = __logf(v.w); return r;
}

// ---------------------------------------------------------------------------
// K1 (wave-autonomous): each wave owns a 16-row tile end-to-end. No barriers
// in the steady-state loop. A-fragments load straight from global in MFMA
// layout; B (actor_w) lives transposed+bf16 in LDS; next_states stream
// through registers for the critic dot only. Softmax/entropy/gather fully
// in-register on the MFMA C-layout.
// ---------------------------------------------------------------------------
__global__ __launch_bounds__(512, 4) void ppo_main(
    const float* __restrict__ states,
    const float* __restrict__ next_states,
    const float* __restrict__ rewards,
    const int*   __restrict__ dones,
    const int*   __restrict__ actions,
    const float* __restrict__ log_probs,
    const float* __restrict__ actor_w,
    const float* __restrict__ actor_b,
    const float* __restrict__ critic_w,
    const float* __restrict__ critic_b,
    float* __restrict__ d_delta,
    float* __restrict__ d_ratio,
    float* __restrict__ acc) {
  __shared__ bf16_t sBt[A_DIM * LDBT];   // 66,560 B: Bt[col][k], bf16
  __shared__ float  sCW[S_DIM];          // 2 KB

  const int t    = threadIdx.x;
  const int wave = t >> 6;
  const int lane = t & 63;
  const int q    = lane >> 4;   // 0..3 : k-slice within ktile / row-quad in C
  const int r    = lane & 15;   // 0..15: A row / B col / C col

  // ---- one-time staging: critic weights + transposed bf16 actor weights ----
  for (int i = t; i < S_DIM; i += 512) sCW[i] = critic_w[i];
  for (int i = t; i < S_DIM * A_DIM; i += 512)
    sBt[(i & 63) * LDBT + (i >> 6)] = (bf16_t)actor_w[i];

  const float cb = critic_b[0];
  const float b0 = actor_b[r], b1 = actor_b[16 + r];
  const float b2 = actor_b[32 + r], b3 = actor_b[48 + r];
  __syncthreads();

  // per-lane B fragment bases (coltile n): Bt[16n + r][k = 32kt + 8q + j]
  const bf16_t* bp0 = &sBt[(r +  0) * LDBT + (q << 3)];
  const bf16_t* bp1 = &sBt[(r + 16) * LDBT + (q << 3)];
  const bf16_t* bp2 = &sBt[(r + 32) * LDBT + (q << 3)];
  const bf16_t* bp3 = &sBt[(r + 48) * LDBT + (q << 3)];

  float entloc = 0.f;

  for (int tile = blockIdx.x * 8 + wave; tile < (T_TOT / 16); tile += 4096) {
    const int row0 = tile << 4;
    const float* sp = states      + (size_t)(row0 + r) * S_DIM + (q << 3);
    const float* np = next_states + (size_t)(row0 + r) * S_DIM + (q << 3);

    f32x4 acc0 = {0.f, 0.f, 0.f, 0.f}, acc1 = {0.f, 0.f, 0.f, 0.f};
    f32x4 acc2 = {0.f, 0.f, 0.f, 0.f}, acc3 = {0.f, 0.f, 0.f, 0.f};
    float vp = 0.f, nvp = 0.f;

#pragma unroll
    for (int kt = 0; kt < 16; ++kt) {
      const int o = kt << 5;   // 32 floats per ktile
      f32x4 s0 = *(const f32x4*)(sp + o);
      f32x4 s1 = *(const f32x4*)(sp + o + 4);
      f32x4 n0 = *(const f32x4*)(np + o);
      f32x4 n1 = *(const f32x4*)(np + o + 4);
      const f32x4 w0 = *(const f32x4*)(&sCW[o + (q << 3)]);
      const f32x4 w1 = *(const f32x4*)(&sCW[o + (q << 3) + 4]);
      vp  += dot4(s0, w0) + dot4(s1, w1);
      nvp += dot4(n0, w0) + dot4(n1, w1);
      bf16x8 a;
      a[0] = (bf16_t)s0.x; a[1] = (bf16_t)s0.y; a[2] = (bf16_t)s0.z; a[3] = (bf16_t)s0.w;
      a[4] = (bf16_t)s1.x; a[5] = (bf16_t)s1.y; a[6] = (bf16_t)s1.z; a[7] = (bf16_t)s1.w;
      acc0 = __builtin_amdgcn_mfma_f32_16x16x32_bf16(a, *(const bf16x8*)(bp0 + o), acc0, 0, 0, 0);
      acc1 = __builtin_amdgcn_mfma_f32_16x16x32_bf16(a, *(const bf16x8*)(bp1 + o), acc1, 0, 0, 0);
      acc2 = __builtin_amdgcn_mfma_f32_16x16x32_bf16(a, *(const bf16x8*)(bp2 + o), acc2, 0, 0, 0);
      acc3 = __builtin_amdgcn_mfma_f32_16x16x32_bf16(a, *(const bf16x8*)(bp3 + o), acc3, 0, 0, 0);
    }

    // ---- critic: reduce k-slices over the 4 q-groups; lane holds v[row r] ----
    vp  += __shfl_xor(vp, 16, 64);  vp  += __shfl_xor(vp, 32, 64);
    nvp += __shfl_xor(nvp, 16, 64); nvp += __shfl_xor(nvp, 32, 64);
    const float v_r  = vp + cb;
    const float nv_r = nvp + cb;

    // ---- softmax on C-layout: acc_n[i] = logit[row 4q+i][col 16n+r] ----
    acc0 += b0; acc1 += b1; acc2 += b2; acc3 += b3;

    f32x4 mx = vmax4(vmax4(acc0, acc1), vmax4(acc2, acc3));
#pragma unroll
    for (int m = 8; m; m >>= 1) mx = vmax4(mx, shflx4(mx, m));

    const f32x4 e0 = exp4(acc0 - mx), e1 = exp4(acc1 - mx);
    const f32x4 e2 = exp4(acc2 - mx), e3 = exp4(acc3 - mx);
    f32x4 zs = e0 + e1 + e2 + e3;
#pragma unroll
    for (int m = 8; m; m >>= 1) zs += shflx4(zs, m);

    f32x4 pnum = e0 * (acc0 - mx) + e1 * (acc1 - mx) + e2 * (acc2 - mx) + e3 * (acc3 - mx);
#pragma unroll
    for (int m = 8; m; m >>= 1) pnum += shflx4(pnum, m);

    const f32x4 lz = log4(zs);
    const f32x4 pl = pnum / zs - lz;    // per row i: sum_a p*logp

    // ---- gather new_log_prob at col = action[row] ----
    const int4 av = *(const int4*)(&actions[row0 + (q << 2)]);
    f32x4 g = {0.f, 0.f, 0.f, 0.f};
    g.x += (av.x == r     ) ? (acc0.x - mx.x - lz.x) : 0.f;
    g.x += (av.x == r + 16) ? (acc1.x - mx.x - lz.x) : 0.f;
    g.x += (av.x == r + 32) ? (acc2.x - mx.x - lz.x) : 0.f;
    g.x += (av.x == r + 48) ? (acc3.x - mx.x - lz.x) : 0.f;
    g.y += (av.y == r     ) ? (acc0.y - mx.y - lz.y) : 0.f;
    g.y += (av.y == r + 16) ? (acc1.y - mx.y - lz.y) : 0.f;
    g.y += (av.y == r + 32) ? (acc2.y - mx.y - lz.y) : 0.f;
    g.y += (av.y == r + 48) ? (acc3.y - mx.y - lz.y) : 0.f;
    g.z += (av.z == r     ) ? (acc0.z - mx.z - lz.z) : 0.f;
    g.z += (av.z == r + 16) ? (acc1.z - mx.z - lz.z) : 0.f;
    g.z += (av.z == r + 32) ? (acc2.z - mx.z - lz.z) : 0.f;
    g.z += (av.z == r + 48) ? (acc3.z - mx.z - lz.z) : 0.f;
    g.w += (av.w == r     ) ? (acc0.w - mx.w - lz.w) : 0.f;
    g.w += (av.w == r + 16) ? (acc1.w - mx.w - lz.w) : 0.f;
    g.w += (av.w == r + 32) ? (acc2.w - mx.w - lz.w) : 0.f;
    g.w += (av.w == r + 48) ? (acc3.w - mx.w - lz.w) : 0.f;
#pragma unroll
    for (int m = 8; m; m >>= 1) g += shflx4(g, m);

    // ---- per-row finish: lane (q, r<4) owns global row row0 + 4q + r ----
    const float v_own  = __shfl(v_r,  (q << 2) + r, 64);  // v[row 4q+r]
    const float nv_own = __shfl(nv_r, (q << 2) + r, 64);
    if (r < 4) {
      const int gt = row0 + (q << 2) + r;
      const float nd = 1.f - (float)dones[gt];
      const float pls  = (r == 0) ? pl.x : (r == 1) ? pl.y : (r == 2) ? pl.z : pl.w;
      const float gsel = (r == 0) ? g.x  : (r == 1) ? g.y  : (r == 2) ? g.z  : g.w;
      d_delta[gt] = rewards[gt] + GAMMA * nv_own * nd - v_own;
      d_ratio[gt] = __expf(gsel - log_probs[gt]);
      entloc -= pls;
    }
  }

#pragma unroll
  for (int m = 32; m; m >>= 1) entloc += __shfl_xor(entloc, m, 64);
  if (lane == 0) atomicAdd(&acc[0], entloc);
}

// ---------------------------------------------------------------------------
// GAE as parallel scan of affine maps f_t(x) = delta_t + c_t * x (reverse).
// Segment compose (left earlier in time): (a,b) o (a',b') = (a + b*a', b*b')
// ---------------------------------------------------------------------------
__global__ void gae_block_affine(const float* __restrict__ delta,
                                 const int* __restrict__ dones,
                                 float* __restrict__ blkA, float* __restrict__ blkB) {
  const int t = threadIdx.x;
  const int base = blockIdx.x * 1024 + t * 4;
  float a = 0.f, b = 1.f;
#pragma unroll
  for (int j = 3; j >= 0; --j) {
    const float c = GL * (1.f - (float)dones[base + j]);
    a = delta[base + j] + c * a;
    b = c * b;
  }
  __shared__ float sa[256], sb[256];
  sa[t] = a; sb[t] = b;
  __syncthreads();
  for (int s = 1; s < 256; s <<= 1) {
    if ((t & (2 * s - 1)) == 0) {
      const float ar = sa[t + s], br = sb[t + s];
      sa[t] = sa[t] + sb[t] * ar;
      sb[t] = sb[t] * br;
    }
    __syncthreads();
  }
  if (t == 0) { blkA[blockIdx.x] = sa[0]; blkB[blockIdx.x] = sb[0]; }
}

__global__ void gae_block_scan(const float* __restrict__ blkA,
                               const float* __restrict__ blkB,
                               float* __restrict__ blkIn) {
  const int t = threadIdx.x;  // 256
  __shared__ float sa[256], sb[256];
  sa[t] = blkA[t]; sb[t] = blkB[t];
  __syncthreads();
  for (int d = 1; d < 256; d <<= 1) {
    float na = sa[t], nb = sb[t];
    if (t + d < 256) { na = sa[t] + sb[t] * sa[t + d]; nb = sb[t] * sb[t + d]; }
    __syncthreads();
    sa[t] = na; sb[t] = nb;
    __syncthreads();
  }
  blkIn[t] = (t < 255) ? sa[t + 1] : 0.f;   // adv entering block t from the right
}

__global__ void gae_apply_loss(const float* __restrict__ delta,
                               const int* __restrict__ dones,
                               const float* __restrict__ ratio,
                               const float* __restrict__ blkIn,
                               float* __restrict__ acc) {
  const int t = threadIdx.x;
  const int base = blockIdx.x * 1024 + t * 4;
  float dl[4], cc[4];
#pragma unroll
  for (int j = 0; j < 4; ++j) {
    dl[j] = delta[base + j];
    cc[j] = GL * (1.f - (float)dones[base + j]);
  }
  float a = 0.f, b = 1.f;
#pragma unroll
  for (int j = 3; j >= 0; --j) { a = dl[j] + cc[j] * a; b = cc[j] * b; }

  __shared__ float sa[256], sb[256];
  sa[t] = a; sb[t] = b;
  __syncthreads();
  for (int d = 1; d < 256; d <<= 1) {
    float na = sa[t], nb = sb[t];
    if (t + d < 256) { na = sa[t] + sb[t] * sa[t + d]; nb = sb[t] * sb[t + d]; }
    __syncthreads();
    sa[t] = na; sb[t] = nb;
    __syncthreads();
  }
  float x = blkIn[blockIdx.x];
  if (t < 255) x = sa[t + 1] + sb[t + 1] * x;   // adv entering this thread's segment

  float msum = 0.f, a2 = 0.f;
#pragma unroll
  for (int j = 3; j >= 0; --j) {
    x = dl[j] + cc[j] * x;                      // adv[base+j]
    const float rt = ratio[base + j];
    const float s1 = rt * x;
    const float rc = fminf(fmaxf(rt, CLIP_LO), CLIP_HI);
    const float s2 = rc * x;
    msum += fminf(s1, s2);
    a2 += x * x;
  }
  // block reduce
#pragma unroll
  for (int off = 32; off > 0; off >>= 1) {
    msum += __shfl_down(msum, off, 64);
    a2   += __shfl_down(a2,   off, 64);
  }
  __shared__ float rm[4], ra[4];
  if ((t & 63) == 0) { rm[t >> 6] = msum; ra[t >> 6] = a2; }
  __syncthreads();
  if (t == 0) {
    atomicAdd(&acc[1], rm[0] + rm[1] + rm[2] + rm[3]);
    atomicAdd(&acc[2], ra[0] + ra[1] + ra[2] + ra[3]);
  }
}

__global__ void ppo_finalize(const float* __restrict__ acc, float* __restrict__ out) {
  if (threadIdx.x == 0) {
    const float invT = 1.0f / (float)T_TOT;
    out[0] = -(acc[1] * invT) - ENT_COEF * (acc[0] * invT);
    out[1] = acc[2] * invT;
  }
}

extern "C" void kernel_launch(void* const* d_in, const int* in_sizes, int n_in,
                              void* d_out, int out_size, void* d_ws, size_t ws_size,
                              hipStream_t stream) {
  const float* states      = (const float*)d_in[0];
  const float* next_states = (const float*)d_in[1];
  const float* rewards     = (const float*)d_in[2];
  const int*   dones       = (const int*)d_in[3];
  const int*   actions     = (const int*)d_in[4];
  const float* log_probs   = (const float*)d_in[5];
  const float* actor_w     = (const float*)d_in[6];
  const float* actor_b     = (const float*)d_in[7];
  const float* critic_w    = (const float*)d_in[8];
  const float* critic_b    = (const float*)d_in[9];
  float* out = (float*)d_out;

  char* ws = (char*)d_ws;
  float* delta = (float*)ws;                       // T floats
  float* ratio = (float*)(ws + (size_t)T_TOT * 4); // T floats
  float* blkA  = (float*)(ws + (size_t)2 * T_TOT * 4);
  float* blkB  = blkA + 256;
  float* blkIn = blkB + 256;
  float* acc   = blkIn + 256;                      // [0]=ent, [1]=msum, [2]=adv2

  hipMemsetAsync(acc, 0, 3 * sizeof(float), stream);

  ppo_main<<<512, 512, 0, stream>>>(states, next_states, rewards, dones, actions,
                                    log_probs, actor_w, actor_b, critic_w, critic_b,
                                    delta, ratio, acc);
  gae_block_affine<<<256, 256, 0, stream>>>(delta, dones, blkA, blkB);
  gae_block_scan<<<1, 256, 0, stream>>>(blkA, blkB, blkIn);
  gae_apply_loss<<<256, 256, 0, stream>>>(delta, dones, ratio, blkIn, acc);
  ppo_finalize<<<1, 64, 0, stream>>>(acc, out);
}